// Round 6
// baseline (50.509 us; speedup 1.0000x reference)
//
#include <hip/hip_runtime.h>
#include <hip/hip_bf16.h>
#include <stdint.h>

// Problem constants (fixed by setup_inputs)
#define KC   256      // concepts
#define DD   256      // feature dim
#define NPROT 1024    // KC*M
#define NQ   32768    // B*KC

// ws layout (bytes); ws_size = 256 MB (fill counters). Total used ~22 MB.
#define OFF_TOT  0                        // float
#define OFF_CNT  8                        // float
#define OFF_PN   256                      // bf16 protos k-major: [16 kslabs][1024 rows][32B] (512 KB)
#define OFF_QN   1048576                  // bf16 queries k-major: [16 kslabs][32768 rows][32B] (16 MB)
#define QSLAB    1048576                  // 32768 * 32 B per k-slab
#define OFF_ACC  17825792                 // float[32768][4 chunks][4 waves][2] = 4 MB, collision-free slots

#define LN2F    0.69314718055994531f
#define C10L2E  14.426950408889634f       // 10 * log2(e): folds 1/T into exp2 domain

typedef __bf16 bf16x8 __attribute__((ext_vector_type(8)));
typedef float  f32x16 __attribute__((ext_vector_type(16)));

static __device__ __forceinline__ unsigned short f2bf(float x) {
  __hip_bfloat16 h = __float2bfloat16(x);
  return __builtin_bit_cast(unsigned short, h);
}

// ---------------- Kernel 1: normalize protos AND all queries -> bf16 k-major; zero scalars ----------------
// blocks 0..255: protos (4 rows each). blocks 256..511: queries (128 rows each).
__global__ __launch_bounds__(256) void prep_k(const float* __restrict__ lv,
                                              const float* __restrict__ protos,
                                              unsigned char* __restrict__ ws) {
  const int blk = blockIdx.x;
  if (blk == 0 && threadIdx.x == 0) {
    *(float*)(ws + OFF_TOT) = 0.0f;
    *(float*)(ws + OFF_CNT) = 0.0f;
  }

  if (blk < 256) {
    // ---- prototypes: one row per wave ----
    const int w = threadIdx.x >> 6, lane = threadIdx.x & 63;
    const int r = blk * 4 + w;                     // 1024 rows
    const float4 v = ((const float4*)protos)[r * 64 + lane];
    float ss = v.x*v.x + v.y*v.y + v.z*v.z + v.w*v.w;
#pragma unroll
    for (int m = 1; m < 64; m <<= 1) ss += __shfl_xor(ss, m, 64);
    const float sc = 1.0f / fmaxf(sqrtf(ss), 1e-12f);
    uint2 p;
    p.x = (unsigned)f2bf(v.x * sc) | ((unsigned)f2bf(v.y * sc) << 16);
    p.y = (unsigned)f2bf(v.z * sc) | ((unsigned)f2bf(v.w * sc) << 16);
    // element e = lane*4.. -> slab = e>>4 = lane>>2, byte in slab-row = (lane&3)*8
    *(uint2*)(ws + OFF_PN + (lane >> 2) * 32768 + r * 32 + (lane & 3) * 8) = p;
  } else {
    // ---- queries: 16-lane group per row, 8 rows per group ----
    const int b2  = blk - 256;                     // 0..255 -> 128 rows each
    const int grp = threadIdx.x >> 4, sub = threadIdx.x & 15;
    const int s0  = sub >> 2, c8 = (sub & 3) * 8;
#pragma unroll 2
    for (int t = 0; t < 8; ++t) {
      const int r = b2 * 128 + grp * 8 + t;        // 0..32767
      float4 vv[4];
#pragma unroll
      for (int u = 0; u < 4; ++u) vv[u] = ((const float4*)lv)[r * 64 + u * 16 + sub];
      float ss = 0.0f;
#pragma unroll
      for (int u = 0; u < 4; ++u)
        ss += vv[u].x*vv[u].x + vv[u].y*vv[u].y + vv[u].z*vv[u].z + vv[u].w*vv[u].w;
#pragma unroll
      for (int m = 1; m < 16; m <<= 1) ss += __shfl_xor(ss, m, 64);
      const float sc = 1.0f / fmaxf(sqrtf(ss), 1e-12f);
#pragma unroll
      for (int u = 0; u < 4; ++u) {
        uint2 p;
        p.x = (unsigned)f2bf(vv[u].x * sc) | ((unsigned)f2bf(vv[u].y * sc) << 16);
        p.y = (unsigned)f2bf(vv[u].z * sc) | ((unsigned)f2bf(vv[u].w * sc) << 16);
        // element e = u*64 + sub*4 -> slab = u*4 + (sub>>2), byte = (sub&3)*8
        *(uint2*)(ws + OFF_QN + (u * 4 + s0) * QSLAB + r * 32 + c8) = p;
      }
    }
  }
}

// ---------------- Kernel 2: GEMM (all 32768 queries x 1024 protos) + exp2/pos partials ----------------
// grid: 512 tiles (64 queries) x 4 chunks (256 protos) = 2048 blocks, 256 threads, all active
__global__ __launch_bounds__(256, 4) void main_k(unsigned char* __restrict__ ws) {
  __shared__ __align__(16) unsigned char Aq[64 * 512];  // 64 query rows, bf16, swizzled (32 KB)

  const int tid  = threadIdx.x;
  const int w    = tid >> 6;        // wave 0..3
  const int lane = tid & 63;
  const int hi   = lane >> 5;
  const int l31  = lane & 31;

  const int tile = blockIdx.x >> 2;
  const int c    = blockIdx.x & 3;           // proto chunk of 256 rows

  // A-fragment base: proto rows c*256 + w*64 + h*32 + l31, 16B piece hi
  const unsigned char* pn = ws + OFF_PN + (c * 256 + w * 64 + l31) * 32 + hi * 16;

  // depth-8 prefetch ring for A-frags (steps s = h*16 + k), issued before staging
  bf16x8 pa[8];
#pragma unroll
  for (int p = 0; p < 8; ++p) pa[p] = *(const bf16x8*)(pn + p * 32768);

  // ---- stage 64 query rows (tile*64 ..) from QN into swizzled LDS: pure copy ----
  const unsigned char* qn = ws + OFF_QN;
#pragma unroll
  for (int i = 0; i < 4; ++i) {
    const int unit = i * 256 + tid;          // 1024 units: (slab s, row r)
    const int s = unit >> 6, r = unit & 63;
    const unsigned char* src = qn + s * QSLAB + (tile * 64 + r) * 32;
    const uint4 d0 = *(const uint4*)(src);
    const uint4 d1 = *(const uint4*)(src + 16);
    const int swz = (r & 7) << 4;
    *(uint4*)(Aq + r * 512 + ((s * 32) ^ swz))      = d0;
    *(uint4*)(Aq + r * 512 + ((s * 32 + 16) ^ swz)) = d1;
  }
  __syncthreads();

  float l_acc[2], p_acc[2];
  const int bswz = (l31 & 7) << 4;           // rows l31 and 32+l31 share (row&7)

#pragma unroll
  for (int h = 0; h < 2; ++h) {
    f32x16 acc0, acc1;
#pragma unroll
    for (int t = 0; t < 16; ++t) { acc0[t] = 0.0f; acc1[t] = 0.0f; }

#pragma unroll
    for (int k = 0; k < 16; ++k) {
      const int s = h * 16 + k;
      const bf16x8 a = pa[s & 7];
      if (s < 24)
        pa[s & 7] = *(const bf16x8*)(pn + ((s + 8) >> 4) * 1024 + ((s + 8) & 15) * 32768);
      const int bc = (k * 32 + hi * 16) ^ bswz;
      const bf16x8 b0 = *(const bf16x8*)(Aq + l31 * 512 + bc);
      const bf16x8 b1 = *(const bf16x8*)(Aq + (32 + l31) * 512 + bc);
      acc0 = __builtin_amdgcn_mfma_f32_32x32x16_bf16(a, b0, acc0, 0, 0, 0);
      acc1 = __builtin_amdgcn_mfma_f32_32x32x16_bf16(a, b1, acc1, 0, 0, 0);
    }

    // ---- epilogue for half h: y = sim*10*log2e; L += 2^y; P += y on positives ----
    const int r4base = c * 64 + w * 16 + h * 8 + hi;   // proto row>>2 = r4base + 2*g
#pragma unroll
    for (int j = 0; j < 2; ++j) {
      const int kq = (tile * 64 + j * 32 + l31) & (KC - 1);  // concept of this query column
      float l4[4] = {0.f, 0.f, 0.f, 0.f};
      float p4[4] = {0.f, 0.f, 0.f, 0.f};
#pragma unroll
      for (int g = 0; g < 4; ++g) {
        const float pm = (r4base + 2 * g == kq) ? 1.0f : 0.0f;
#pragma unroll
        for (int t = 0; t < 4; ++t) {
          const float y = ((j == 0) ? acc0[g * 4 + t] : acc1[g * 4 + t]) * C10L2E;
          l4[t] += __builtin_amdgcn_exp2f(y);
          p4[t] = fmaf(pm, y, p4[t]);
        }
      }
      const float ls = (l4[0] + l4[1]) + (l4[2] + l4[3]);
      const float ps = (p4[0] + p4[1]) + (p4[2] + p4[3]);
      if (h == 0) { l_acc[j] = ls;  p_acc[j] = ps; }
      else        { l_acc[j] += ls; p_acc[j] += ps; }
    }
  }

  // combine the two row-half lanes (lane ^ 32); then ONE plain store per (q, chunk, wave):
  // each wave holds only 64 of the chunk's 256 proto rows -> per-wave slots (round-3/5 bug fix).
#pragma unroll
  for (int j = 0; j < 2; ++j) {
    l_acc[j] += __shfl_xor(l_acc[j], 32, 64);
    p_acc[j] += __shfl_xor(p_acc[j], 32, 64);
  }
  if (hi == 0) {
    float* accb = (float*)(ws + OFF_ACC);
#pragma unroll
    for (int j = 0; j < 2; ++j) {
      const int q = tile * 64 + j * 32 + l31;
      float2 v2; v2.x = l_acc[j]; v2.y = p_acc[j];
      *(float2*)(accb + q * 32 + c * 8 + w * 2) = v2;   // [q][c][w][2], no collisions
    }
  }
}

// ---------------- Kernel 3: per-query contribution + count, grid sum into ws ----------------
__global__ __launch_bounds__(256) void finish1_k(const int* __restrict__ gt,
                                                 unsigned char* __restrict__ ws) {
  __shared__ float accs[4], accn[4];
  const int i = blockIdx.x * 256 + threadIdx.x;   // 128 blocks -> 32768
  float contrib = 0.0f, cnt = 0.0f;
  if (gt[i] == 1) {
    const float* a = (const float*)(ws + OFF_ACC) + i * 32;  // 16 {l,p} pairs
    float L = 0.0f, P = 0.0f;
#pragma unroll
    for (int u = 0; u < 8; ++u) {
      const float4 v = *(const float4*)(a + u * 4);
      L += v.x + v.z;
      P += v.y + v.w;
    }
    contrib = LN2F * (4.0f * __builtin_amdgcn_logf(L) - P);  // logf = log2 on gfx950
    cnt = 1.0f;
  }
#pragma unroll
  for (int m = 1; m < 64; m <<= 1) {
    contrib += __shfl_xor(contrib, m, 64);
    cnt     += __shfl_xor(cnt, m, 64);
  }
  if ((threadIdx.x & 63) == 0) { accs[threadIdx.x >> 6] = contrib; accn[threadIdx.x >> 6] = cnt; }
  __syncthreads();
  if (threadIdx.x == 0) {
    atomicAdd((float*)(ws + OFF_TOT), (accs[0] + accs[1]) + (accs[2] + accs[3]));
    atomicAdd((float*)(ws + OFF_CNT), (accn[0] + accn[1]) + (accn[2] + accn[3]));
  }
}

// ---------------- Kernel 4: final divide ----------------
__global__ __launch_bounds__(64) void finish2_k(const unsigned char* __restrict__ ws,
                                                float* __restrict__ out) {
  if (threadIdx.x == 0) {
    const float total = *(const float*)(ws + OFF_TOT);
    const float cnt   = *(const float*)(ws + OFF_CNT);
    out[0] = (cnt > 0.0f) ? total / (4.0f * cnt) : 0.0f;
  }
}

extern "C" void kernel_launch(void* const* d_in, const int* in_sizes, int n_in,
                              void* d_out, int out_size, void* d_ws, size_t ws_size,
                              hipStream_t stream) {
  const float* lv     = (const float*)d_in[0];   // (128,256,256) f32
  const float* protos = (const float*)d_in[1];   // (1024,256,1,1) f32
  const int*   gt     = (const int*)d_in[2];     // (128,256) i32
  (void)in_sizes; (void)n_in; (void)out_size; (void)ws_size;
  unsigned char* ws = (unsigned char*)d_ws;

  prep_k<<<512, 256, 0, stream>>>(lv, protos, ws);
  main_k<<<2048, 256, 0, stream>>>(ws);
  finish1_k<<<128, 256, 0, stream>>>(gt, ws);
  finish2_k<<<1, 64, 0, stream>>>(ws, (float*)d_out);
}